// Round 5
// baseline (2388.076 us; speedup 1.0000x reference)
//
#include <hip/hip_runtime.h>
#include <hip/hip_bf16.h>
#include <stdint.h>

// out[m][n] = (sum_k x[m][k] * W[n][k]) * scale[n]
// M=8192 (B*S), N=4096 (D_OUT), K=4096 (D_IN)
// x fp32, W int32 (harness materializes integer inputs as int32), scale fp32.
// Path: x->bf16, W->bf16 in ws, then 256x256-tile MFMA GEMM, BK=32,
// LDS 64 KiB -> 2 blocks/CU: cross-block LDS/MFMA overlap (m114 mechanism).
// 2 phases/K-tile, deferred in-place staging, counted vmcnt(3), T1 XCD
// swizzle, chunk-XOR LDS swizzle (both-sides), T5 setprio.

#define M_TOT 8192
#define N_TOT 4096
#define K_TOT 4096
#define BM 256
#define BN 256
#define BK 32
#define NT (K_TOT / BK)   // 128 k-tiles

typedef short short8 __attribute__((ext_vector_type(8)));
typedef __bf16 bf16x8 __attribute__((ext_vector_type(8)));
typedef float floatx4 __attribute__((ext_vector_type(4)));

__device__ __forceinline__ short f32bits_to_bf16_rne(unsigned u) {
  unsigned r = u + 0x7fffu + ((u >> 16) & 1u);
  return (short)(r >> 16);
}
__device__ __forceinline__ short i32_to_bf16(int v) {
  float f = (float)v;
  return f32bits_to_bf16_rne(__builtin_bit_cast(unsigned, f));
}

// ---- conversion kernels ----
__global__ void cvt_x_kernel(const uint4* __restrict__ in, short8* __restrict__ out) {
  int i = blockIdx.x * blockDim.x + threadIdx.x;
  uint4 a = in[2 * i];
  uint4 b = in[2 * i + 1];
  short8 o;
  o[0] = f32bits_to_bf16_rne(a.x); o[1] = f32bits_to_bf16_rne(a.y);
  o[2] = f32bits_to_bf16_rne(a.z); o[3] = f32bits_to_bf16_rne(a.w);
  o[4] = f32bits_to_bf16_rne(b.x); o[5] = f32bits_to_bf16_rne(b.y);
  o[6] = f32bits_to_bf16_rne(b.z); o[7] = f32bits_to_bf16_rne(b.w);
  out[i] = o;
}
__global__ void cvt_w_kernel(const int4* __restrict__ in, short8* __restrict__ out) {
  int i = blockIdx.x * blockDim.x + threadIdx.x;
  int4 a = in[2 * i];
  int4 b = in[2 * i + 1];
  short8 o;
  o[0] = i32_to_bf16(a.x); o[1] = i32_to_bf16(a.y);
  o[2] = i32_to_bf16(a.z); o[3] = i32_to_bf16(a.w);
  o[4] = i32_to_bf16(b.x); o[5] = i32_to_bf16(b.y);
  o[6] = i32_to_bf16(b.z); o[7] = i32_to_bf16(b.w);
  out[i] = o;
}

// ---- async global->LDS (16B per lane, wave-uniform dest + lane*16) ----
__device__ __forceinline__ void gload_lds16(const void* g, const void* l) {
  const __attribute__((address_space(1))) void* gp =
      reinterpret_cast<const __attribute__((address_space(1))) void*>(
          reinterpret_cast<uintptr_t>(g));
  __attribute__((address_space(3))) void* lp =
      reinterpret_cast<__attribute__((address_space(3))) void*>(
          (uint32_t)reinterpret_cast<uintptr_t>(l));
  __builtin_amdgcn_global_load_lds(gp, lp, 16, 0, 0);
}

#define BAR() __builtin_amdgcn_s_barrier()

// ---- main GEMM: 256x256 tile, BK=32, 8 waves (2x4), 2 phases/k-tile ----
__global__ __launch_bounds__(512, 4)
void wq_gemm_kernel(const short* __restrict__ A,     // [M][K] bf16
                    const short* __restrict__ B,     // [N][K] bf16 (W rows)
                    const float* __restrict__ scale, // [N]
                    float* __restrict__ C) {         // [M][N]
  // [dbuf][256 rows][32 k] bf16 = 16 KiB per operand per buf -> 64 KiB total.
  __shared__ __align__(16) short As[2][BM * BK];
  __shared__ __align__(16) short Bs[2][BN * BK];

  // XCD-aware block swizzle (nwg=512, divisible by 8)
  const int nb = gridDim.x;
  const int swz = (blockIdx.x & 7) * (nb >> 3) + (blockIdx.x >> 3);
  const int bm = swz >> 4;        // M/BM = 32
  const int bn = swz & 15;        // N/BN = 16

  const int tid = threadIdx.x;
  const int wave = tid >> 6, lane = tid & 63;
  const int wr = wave >> 2, wc = wave & 3;   // 2 x 4 wave grid
  const int l15 = lane & 15, lk = lane >> 4;
  const int wr16l = wr * 16 + l15;
  const int wc16l = wc * 16 + l15;
  // read-side swizzled chunk (0..3), constant per lane
  const int rchunk = (lk ^ ((l15 >> 1) & 3)) << 3;   // in shorts

  floatx4 acc[8][4] = {};
  bf16x8 afL[4], afH[4], bf[4];

  // Staging: one gload = 512 threads x 16B = 128 rows x 64B (full half-tile).
  // LDS dest linear; global source chunk pre-swizzled (involution).
  const int srow = tid >> 2;                          // 0..127
  const int sc = (tid & 3) ^ ((tid >> 3) & 3);        // source 16B-chunk
  const short* gA = A + (size_t)(bm * BM + srow) * K_TOT + sc * 8;
  const short* gB = B + (size_t)(bn * BN + srow) * K_TOT + sc * 8;

#define STAGE_A(p, h, kt)                                                 \
  gload_lds16(gA + (size_t)(h) * 128 * K_TOT + (kt) * BK,                 \
              (const char*)As[p] + (h) * 8192 + wave * 1024)
#define STAGE_B(p, h, kt)                                                 \
  gload_lds16(gB + (size_t)(h) * 128 * K_TOT + (kt) * BK,                 \
              (const char*)Bs[p] + (h) * 8192 + wave * 1024)

  // Swizzled fragment read: row*32 shorts + swizzled 16B chunk.
#define DS8(BASE, ROW)                                                    \
  __builtin_bit_cast(bf16x8, *(const short8*)((BASE) + (ROW) * BK + rchunk))

#define LD_AFL(P)                                                         \
  _Pragma("unroll") for (int mi = 0; mi < 4; ++mi)                        \
      afL[mi] = DS8(As[P], mi * 32 + wr16l);
#define LD_AFH(P)                                                         \
  _Pragma("unroll") for (int mi = 0; mi < 4; ++mi)                        \
      afH[mi] = DS8(As[P], (mi + 4) * 32 + wr16l);
#define LD_BF(P)                                                          \
  _Pragma("unroll") for (int ni = 0; ni < 4; ++ni)                        \
      bf[ni] = DS8(Bs[P], ni * 64 + wc16l);

  // Half: 4 mi x 4 ni = 16 MFMA (K=32 each).
#define MFMA_H(AF, H)                                                     \
  __builtin_amdgcn_s_setprio(1);                                          \
  _Pragma("unroll") for (int mi2 = 0; mi2 < 4; ++mi2)                     \
  _Pragma("unroll") for (int ni2 = 0; ni2 < 4; ++ni2)                     \
      acc[(H) * 4 + mi2][ni2] =                                           \
          __builtin_amdgcn_mfma_f32_16x16x32_bf16(                        \
              AF[mi2], bf[ni2], acc[(H) * 4 + mi2][ni2], 0, 0, 0);        \
  __builtin_amdgcn_s_setprio(0)

  // ---- prologue: t0 fully (4 gloads), t1 minus A-h1 (3 gloads) ----
  STAGE_A(0, 0, 0); STAGE_A(0, 1, 0); STAGE_B(0, 0, 0); STAGE_B(0, 1, 0);
  STAGE_A(1, 0, 1); STAGE_B(1, 0, 1); STAGE_B(1, 1, 1);
  asm volatile("s_waitcnt vmcnt(3)" ::: "memory");  // t0's 4 landed
  BAR();

  // ---- main loop ----
  // tile t (buf P): ph0 {read A-low+B; deferred-stage t+1 A-h1 into Q;
  //                      BAR; MFMA low; BAR}
  //                 ph1 {read A-high; stage t+2 A-h0,B-h0,B-h1 into P;
  //                      vmcnt(3); BAR; MFMA high; BAR}
  // In-place staging only touches regions certified read-done by a prior BAR.
#define TILE(P, Q, T)                                                      \
  do {                                                                     \
    /* ph0 */                                                              \
    LD_AFL(P);                                                             \
    LD_BF(P);                                                              \
    if ((T) + 1 < NT) { STAGE_A(Q, 1, (T) + 1); }                          \
    BAR();                                                                 \
    MFMA_H(afL, 0);                                                        \
    BAR();                                                                 \
    /* ph1 */                                                              \
    LD_AFH(P);                                                             \
    if ((T) + 2 < NT) {                                                    \
      STAGE_A(P, 0, (T) + 2);                                              \
      STAGE_B(P, 0, (T) + 2);                                              \
      STAGE_B(P, 1, (T) + 2);                                              \
      asm volatile("s_waitcnt vmcnt(3)" ::: "memory");                     \
    } else if ((T) + 1 < NT) {                                             \
      asm volatile("s_waitcnt vmcnt(0)" ::: "memory");                     \
    }                                                                      \
    BAR();                                                                 \
    MFMA_H(afH, 1);                                                        \
    BAR();                                                                 \
  } while (0)

  for (int t = 0; t < NT; t += 2) {
    TILE(0, 1, t);
    TILE(1, 0, t + 1);
  }
#undef TILE

  // ---- epilogue: D mapping col=lane&15, row=(lane>>4)*4+e; fuse scale ----
  const size_t crow0 = (size_t)bm * BM + wr * 16 + (lk << 2);
  const int ccol0 = bn * BN + wc * 16 + l15;
#pragma unroll
  for (int ni = 0; ni < 4; ++ni) {
    const int col = ccol0 + ni * 64;
    const float s = scale[col];
#pragma unroll
    for (int mi = 0; mi < 8; ++mi) {
      const size_t r = crow0 + (size_t)mi * 32;
#pragma unroll
      for (int e = 0; e < 4; ++e)
        C[(r + e) * N_TOT + col] = acc[mi][ni][e] * s;
    }
  }
}

// ---- fallback if workspace too small ----
__global__ void naive_kernel(const float* __restrict__ x,
                             const int* __restrict__ w,
                             const float* __restrict__ s,
                             float* __restrict__ out) {
  int m = blockIdx.y;
  int n = blockIdx.x * 256 + threadIdx.x;
  const float* xr = x + (size_t)m * K_TOT;
  const int* wr = w + (size_t)n * K_TOT;
  float acc = 0.f;
  for (int k = 0; k < K_TOT; ++k) acc += xr[k] * (float)wr[k];
  out[(size_t)m * N_TOT + n] = acc * s[n];
}

extern "C" void kernel_launch(void* const* d_in, const int* in_sizes, int n_in,
                              void* d_out, int out_size, void* d_ws, size_t ws_size,
                              hipStream_t stream) {
  const float* x = (const float*)d_in[0];
  const int* w = (const int*)d_in[1];
  const float* scale = (const float*)d_in[2];
  float* out = (float*)d_out;

  const size_t x_elems = (size_t)M_TOT * K_TOT;
  const size_t w_elems = (size_t)N_TOT * K_TOT;
  const size_t need = (x_elems + w_elems) * sizeof(short);

  if (ws_size < need) {
    dim3 g(N_TOT / 256, M_TOT);
    naive_kernel<<<g, 256, 0, stream>>>(x, w, scale, out);
    return;
  }

  short* xb = (short*)d_ws;
  short* wb = xb + x_elems;

  cvt_x_kernel<<<(int)(x_elems / 8 / 256), 256, 0, stream>>>(
      (const uint4*)x, (short8*)xb);
  cvt_w_kernel<<<(int)(w_elems / 8 / 256), 256, 0, stream>>>(
      (const int4*)w, (short8*)wb);

  wq_gemm_kernel<<<(M_TOT / BM) * (N_TOT / BN), 512, 0, stream>>>(
      xb, wb, scale, out);
}

// Round 6
// 687.314 us; speedup vs baseline: 3.4745x; 3.4745x over previous
//
#include <hip/hip_runtime.h>
#include <hip/hip_bf16.h>
#include <stdint.h>

// out[m][n] = (sum_k x[m][k] * W[n][k]) * scale[n]
// M=8192 (B*S), N=4096 (D_OUT), K=4096 (D_IN)
// x fp32, W int32 (harness materializes integer inputs as int32), scale fp32.
// Path: x->bf16, W->bf16 in ws, then 256x256-tile MFMA GEMM where:
//   A (activations) goes through LDS (4-buffer rotation, 4x32 KiB, swizzled),
//   B (weights) streams global->registers (per-lane 16B fragment loads,
//   L2/L3-hot W panel), double-buffered, counted vmcnt(4) never 0 mid-loop.
// 2 phases per K-tile, 32 MFMA per barrier-pair. T1 XCD swizzle, T5 setprio.

#define M_TOT 8192
#define N_TOT 4096
#define K_TOT 4096
#define BM 256
#define BN 256
#define BK 64
#define NT (K_TOT / BK)   // 64 k-tiles

typedef short short8 __attribute__((ext_vector_type(8)));
typedef __bf16 bf16x8 __attribute__((ext_vector_type(8)));
typedef float floatx4 __attribute__((ext_vector_type(4)));

__device__ __forceinline__ short f32bits_to_bf16_rne(unsigned u) {
  unsigned r = u + 0x7fffu + ((u >> 16) & 1u);
  return (short)(r >> 16);
}
__device__ __forceinline__ short i32_to_bf16(int v) {
  float f = (float)v;
  return f32bits_to_bf16_rne(__builtin_bit_cast(unsigned, f));
}

// ---- conversion kernels ----
__global__ void cvt_x_kernel(const uint4* __restrict__ in, short8* __restrict__ out) {
  int i = blockIdx.x * blockDim.x + threadIdx.x;
  uint4 a = in[2 * i];
  uint4 b = in[2 * i + 1];
  short8 o;
  o[0] = f32bits_to_bf16_rne(a.x); o[1] = f32bits_to_bf16_rne(a.y);
  o[2] = f32bits_to_bf16_rne(a.z); o[3] = f32bits_to_bf16_rne(a.w);
  o[4] = f32bits_to_bf16_rne(b.x); o[5] = f32bits_to_bf16_rne(b.y);
  o[6] = f32bits_to_bf16_rne(b.z); o[7] = f32bits_to_bf16_rne(b.w);
  out[i] = o;
}
__global__ void cvt_w_kernel(const int4* __restrict__ in, short8* __restrict__ out) {
  int i = blockIdx.x * blockDim.x + threadIdx.x;
  int4 a = in[2 * i];
  int4 b = in[2 * i + 1];
  short8 o;
  o[0] = i32_to_bf16(a.x); o[1] = i32_to_bf16(a.y);
  o[2] = i32_to_bf16(a.z); o[3] = i32_to_bf16(a.w);
  o[4] = i32_to_bf16(b.x); o[5] = i32_to_bf16(b.y);
  o[6] = i32_to_bf16(b.z); o[7] = i32_to_bf16(b.w);
  out[i] = o;
}

// ---- async global->LDS (16B per lane, wave-uniform dest + lane*16) ----
__device__ __forceinline__ void gload_lds16(const void* g, const void* l) {
  const __attribute__((address_space(1))) void* gp =
      reinterpret_cast<const __attribute__((address_space(1))) void*>(
          reinterpret_cast<uintptr_t>(g));
  __attribute__((address_space(3))) void* lp =
      reinterpret_cast<__attribute__((address_space(3))) void*>(
          (uint32_t)reinterpret_cast<uintptr_t>(l));
  __builtin_amdgcn_global_load_lds(gp, lp, 16, 0, 0);
}

#define BAR() __builtin_amdgcn_s_barrier()

// ---- main GEMM: 256x256 tile, 8 waves (2x4), 2 phases/k-tile ----
__global__ __launch_bounds__(512, 2)
void wq_gemm_kernel(const short* __restrict__ A,     // [M][K] bf16
                    const short* __restrict__ B,     // [N][K] bf16 (W rows)
                    const float* __restrict__ scale, // [N]
                    float* __restrict__ C) {         // [M][N]
  // A only: 4-buffer rotation, [buf][256 rows][64 k] bf16 = 4 x 32 KiB.
  __shared__ __align__(16) short As[4][BM * BK];

  // XCD-aware block swizzle (nwg=512, divisible by 8)
  const int nb = gridDim.x;
  const int swz = (blockIdx.x & 7) * (nb >> 3) + (blockIdx.x >> 3);
  const int bm = swz >> 4;        // M/BM = 32
  const int bn = swz & 15;        // N/BN = 16

  const int tid = threadIdx.x;
  const int wave = tid >> 6, lane = tid & 63;
  const int wr = wave >> 2, wc = wave & 3;   // 2 x 4 wave grid
  const int l15 = lane & 15, l7 = lane & 7, lk = lane >> 4;
  const int wr16l = wr * 16 + l15;
  const int wc16l = wc * 16 + l15;

  floatx4 acc[8][4] = {};
  bf16x8 af[4][2];                 // current A half (4 m-frags x 2 kk)
  bf16x8 bfA[4][2], bfB[4][2];     // B frags, ping-pong per tile

  // A staging: one gload = 512 threads x 16B = 64 rows x 128B; 4 per K-tile.
  // LDS dest linear; global source chunk pre-swizzled (involution, rule 21).
  const int srow = tid >> 3;                       // 0..63
  const int sc16 = (tid & 7) ^ ((tid >> 3) & 7);
  const short* gA = A + (size_t)(bm * BM + srow) * K_TOT + sc16 * 8;
  // B streaming: per-lane fragment base; row = bn*256 + ni*64 + wc16l,
  // k-chunk = (lk + 4*kk)*8 -> lk*8 + kk*32.
  const short* gB = B + (size_t)(bn * BN + wc16l) * K_TOT + lk * 8;

#define STAGE_A(P, J, KT)                                                 \
  gload_lds16(gA + (size_t)(J) * 64 * K_TOT + (KT) * BK,                  \
              (const char*)As[P] + (J) * 8192 + wave * 1024)
#define STAGE_A4(P, KT)                                                   \
  do { STAGE_A(P, 0, KT); STAGE_A(P, 1, KT);                              \
       STAGE_A(P, 2, KT); STAGE_A(P, 3, KT); } while (0)

  // Swizzled A fragment read: phys 16B-chunk = (lk + 4*kk) ^ (row&7);
  // frag rows are multiples of 8 + l15 -> row&7 == l7.
#define DS8(P, ROW, KK)                                                   \
  __builtin_bit_cast(bf16x8, *(const short8*)(As[P] + (ROW) * BK +        \
                              (((lk + 4 * (KK)) ^ l7) << 3)))

#define LD_AF(P, H)                                                       \
  _Pragma("unroll") for (int mi = 0; mi < 4; ++mi) {                      \
    af[mi][0] = DS8(P, ((H) * 4 + mi) * 32 + wr16l, 0);                   \
    af[mi][1] = DS8(P, ((H) * 4 + mi) * 32 + wr16l, 1);                   \
  }

  // B fragment stream from global (8 x b128 per tile per lane).
#define LD_BG(BF, T)                                                      \
  _Pragma("unroll") for (int ni = 0; ni < 4; ++ni)                        \
  _Pragma("unroll") for (int kk = 0; kk < 2; ++kk)                        \
      BF[ni][kk] = __builtin_bit_cast(                                    \
          bf16x8, *(const short8*)(gB + (size_t)ni * 64 * K_TOT +         \
                                   (size_t)(T) * BK + kk * 32));

  // Half-tile MFMA burst: 4 mi x 4 ni x 2 kk = 32 MFMA.
#define MFMA32(BF, H)                                                     \
  __builtin_amdgcn_s_setprio(1);                                          \
  _Pragma("unroll") for (int mi2 = 0; mi2 < 4; ++mi2)                     \
  _Pragma("unroll") for (int ni2 = 0; ni2 < 4; ++ni2)                     \
  _Pragma("unroll") for (int kk2 = 0; kk2 < 2; ++kk2)                     \
      acc[(H) * 4 + mi2][ni2] =                                           \
          __builtin_amdgcn_mfma_f32_16x16x32_bf16(                        \
              af[mi2][kk2], BF[ni2][kk2],                                 \
              acc[(H) * 4 + mi2][ni2], 0, 0, 0);                          \
  __builtin_amdgcn_s_setprio(0)

  // ---- prologue: A(0), B(0), A(1); certify A(0)+B(0), leave A(1) ----
  STAGE_A4(0, 0);
  LD_BG(bfA, 0);
  STAGE_A4(1, 1);
  asm volatile("s_waitcnt vmcnt(4)" ::: "memory");
  BAR();

  // ---- main loop: tile t reads As[t&3] + BFC; issues B(t+1)->BFN then
  //      A(t+2)->As[(t+2)&3]; ph1 waits vmcnt(4) (A(t+1)+B(t+1) certified,
  //      A(t+2) stays in flight). ----
#define TILE(P, BFC, BFN, T)                                               \
  do {                                                                     \
    /* ph0 */                                                              \
    LD_AF(P, 0);                                                           \
    if ((T) + 1 < NT) { LD_BG(BFN, (T) + 1); }                             \
    if ((T) + 2 < NT) { STAGE_A4((P + 2) & 3, (T) + 2); }                  \
    BAR();                                                                 \
    MFMA32(BFC, 0);                                                        \
    BAR();                                                                 \
    /* ph1 */                                                              \
    LD_AF(P, 1);                                                           \
    if ((T) + 2 < NT) {                                                    \
      asm volatile("s_waitcnt vmcnt(4)" ::: "memory");                     \
    } else {                                                               \
      asm volatile("s_waitcnt vmcnt(0)" ::: "memory");                     \
    }                                                                      \
    BAR();                                                                 \
    MFMA32(BFC, 1);                                                        \
    BAR();                                                                 \
  } while (0)

  for (int t = 0; t < NT; t += 4) {
    TILE(0, bfA, bfB, t);
    TILE(1, bfB, bfA, t + 1);
    TILE(2, bfA, bfB, t + 2);
    TILE(3, bfB, bfA, t + 3);
  }
#undef TILE

  // ---- epilogue: D mapping col=lane&15, row=(lane>>4)*4+e; fuse scale ----
  const size_t crow0 = (size_t)bm * BM + wr * 16 + (lk << 2);
  const int ccol0 = bn * BN + wc * 16 + l15;
#pragma unroll
  for (int ni = 0; ni < 4; ++ni) {
    const int col = ccol0 + ni * 64;
    const float s = scale[col];
#pragma unroll
    for (int mi = 0; mi < 8; ++mi) {
      const size_t r = crow0 + (size_t)mi * 32;
#pragma unroll
      for (int e = 0; e < 4; ++e)
        C[(r + e) * N_TOT + col] = acc[mi][ni][e] * s;
    }
  }
}

// ---- fallback if workspace too small ----
__global__ void naive_kernel(const float* __restrict__ x,
                             const int* __restrict__ w,
                             const float* __restrict__ s,
                             float* __restrict__ out) {
  int m = blockIdx.y;
  int n = blockIdx.x * 256 + threadIdx.x;
  const float* xr = x + (size_t)m * K_TOT;
  const int* wr = w + (size_t)n * K_TOT;
  float acc = 0.f;
  for (int k = 0; k < K_TOT; ++k) acc += xr[k] * (float)wr[k];
  out[(size_t)m * N_TOT + n] = acc * s[n];
}

extern "C" void kernel_launch(void* const* d_in, const int* in_sizes, int n_in,
                              void* d_out, int out_size, void* d_ws, size_t ws_size,
                              hipStream_t stream) {
  const float* x = (const float*)d_in[0];
  const int* w = (const int*)d_in[1];
  const float* scale = (const float*)d_in[2];
  float* out = (float*)d_out;

  const size_t x_elems = (size_t)M_TOT * K_TOT;
  const size_t w_elems = (size_t)N_TOT * K_TOT;
  const size_t need = (x_elems + w_elems) * sizeof(short);

  if (ws_size < need) {
    dim3 g(N_TOT / 256, M_TOT);
    naive_kernel<<<g, 256, 0, stream>>>(x, w, scale, out);
    return;
  }

  short* xb = (short*)d_ws;
  short* wb = xb + x_elems;

  cvt_x_kernel<<<(int)(x_elems / 8 / 256), 256, 0, stream>>>(
      (const uint4*)x, (short8*)xb);
  cvt_w_kernel<<<(int)(w_elems / 8 / 256), 256, 0, stream>>>(
      (const int4*)w, (short8*)wb);

  wq_gemm_kernel<<<(M_TOT / BM) * (N_TOT / BN), 512, 0, stream>>>(
      xb, wb, scale, out);
}

// Round 7
// 266.480 us; speedup vs baseline: 8.9616x; 2.5792x over previous
//
#include <hip/hip_runtime.h>
#include <hip/hip_bf16.h>
#include <stdint.h>

// out[m][n] = (sum_k x[m][k] * W[n][k]) * scale[n]
// M=8192 (B*S), N=4096 (D_OUT), K=4096 (D_IN)
// x fp32, W int32 (harness materializes integer inputs as int32), scale fp32.
// Path: x->bf16, W->bf16 in ws, then 256x256-tile MFMA GEMM, faithful m201
// 8-phase schedule: balanced 8/4/8/4 ds_reads/phase (snaked quadrants, B
// slot read one phase early), exactly one half-tile (2 gloads) staged per
// phase, vmcnt(6) at ph4/ph8 placed BEFORE the next-tile B ds_read.
// T1 XCD swizzle, T2 XOR-chunk LDS swizzle (both sides), T5 setprio.

#define M_TOT 8192
#define N_TOT 4096
#define K_TOT 4096
#define BM 256
#define BN 256
#define BK 64
#define NT (K_TOT / BK)   // 64 k-tiles

typedef short short8 __attribute__((ext_vector_type(8)));
typedef __bf16 bf16x8 __attribute__((ext_vector_type(8)));
typedef float floatx4 __attribute__((ext_vector_type(4)));

__device__ __forceinline__ short f32bits_to_bf16_rne(unsigned u) {
  unsigned r = u + 0x7fffu + ((u >> 16) & 1u);
  return (short)(r >> 16);
}
__device__ __forceinline__ short i32_to_bf16(int v) {
  float f = (float)v;
  return f32bits_to_bf16_rne(__builtin_bit_cast(unsigned, f));
}

// ---- conversion kernels ----
__global__ void cvt_x_kernel(const uint4* __restrict__ in, short8* __restrict__ out) {
  int i = blockIdx.x * blockDim.x + threadIdx.x;
  uint4 a = in[2 * i];
  uint4 b = in[2 * i + 1];
  short8 o;
  o[0] = f32bits_to_bf16_rne(a.x); o[1] = f32bits_to_bf16_rne(a.y);
  o[2] = f32bits_to_bf16_rne(a.z); o[3] = f32bits_to_bf16_rne(a.w);
  o[4] = f32bits_to_bf16_rne(b.x); o[5] = f32bits_to_bf16_rne(b.y);
  o[6] = f32bits_to_bf16_rne(b.z); o[7] = f32bits_to_bf16_rne(b.w);
  out[i] = o;
}
__global__ void cvt_w_kernel(const int4* __restrict__ in, short8* __restrict__ out) {
  int i = blockIdx.x * blockDim.x + threadIdx.x;
  int4 a = in[2 * i];
  int4 b = in[2 * i + 1];
  short8 o;
  o[0] = i32_to_bf16(a.x); o[1] = i32_to_bf16(a.y);
  o[2] = i32_to_bf16(a.z); o[3] = i32_to_bf16(a.w);
  o[4] = i32_to_bf16(b.x); o[5] = i32_to_bf16(b.y);
  o[6] = i32_to_bf16(b.z); o[7] = i32_to_bf16(b.w);
  out[i] = o;
}

// ---- async global->LDS (16B per lane, wave-uniform dest + lane*16) ----
__device__ __forceinline__ void gload_lds16(const void* g, const void* l) {
  const __attribute__((address_space(1))) void* gp =
      reinterpret_cast<const __attribute__((address_space(1))) void*>(
          reinterpret_cast<uintptr_t>(g));
  __attribute__((address_space(3))) void* lp =
      reinterpret_cast<__attribute__((address_space(3))) void*>(
          (uint32_t)reinterpret_cast<uintptr_t>(l));
  __builtin_amdgcn_global_load_lds(gp, lp, 16, 0, 0);
}

#define BAR() __builtin_amdgcn_s_barrier()
#define VMCNT(N) asm volatile("s_waitcnt vmcnt(" #N ")" ::: "memory")

// ---- main GEMM: 256x256 tile, 8 waves (2x4), m201 8-phase schedule ----
__global__ __launch_bounds__(512, 2)
void wq_gemm_kernel(const short* __restrict__ A,     // [M][K] bf16
                    const short* __restrict__ B,     // [N][K] bf16 (W rows)
                    const float* __restrict__ scale, // [N]
                    float* __restrict__ C) {         // [M][N]
  __shared__ __align__(16) short As[2][BM * BK];  // 64 KiB
  __shared__ __align__(16) short Bs[2][BN * BK];  // 64 KiB

  // XCD-aware block swizzle (nwg=512, divisible by 8)
  const int nb = gridDim.x;
  const int swz = (blockIdx.x & 7) * (nb >> 3) + (blockIdx.x >> 3);
  const int bm = swz >> 4;        // M/BM = 32
  const int bn = swz & 15;        // N/BN = 16

  const int tid = threadIdx.x;
  const int wave = tid >> 6, lane = tid & 63;
  const int wr = wave >> 2, wc = wave & 3;   // 2 x 4 wave grid
  const int l15 = lane & 15, l7 = lane & 7, lk = lane >> 4;
  const int wr16l = wr * 16 + l15;
  const int wc16l = wc * 16 + l15;

  floatx4 acc[8][4] = {};
  bf16x8 af[4][2];      // current A half (overwritten per half)
  bf16x8 bf[2][2][2];   // [slot: n01/n23][ni][kk], slots ping-pong

  // Staging: one gload = 512 threads x 16B = 64 rows x 128B.
  // LDS dest linear; global source chunk pre-swizzled (involution, rule 21).
  const int srow = tid >> 3;                       // 0..63
  const int sc16 = (tid & 7) ^ ((tid >> 3) & 7);
  const short* gA = A + (size_t)(bm * BM + srow) * K_TOT + sc16 * 8;
  const short* gB = B + (size_t)(bn * BN + srow) * K_TOT + sc16 * 8;

  // J = 64-row chunk index (0..3). Half h = chunks {2h, 2h+1}.
#define STAGE_A(P, J, KT)                                                 \
  gload_lds16(gA + (size_t)(J) * 64 * K_TOT + (size_t)(KT) * BK,          \
              (const char*)As[P] + (J) * 8192 + wave * 1024)
#define STAGE_B(P, J, KT)                                                 \
  gload_lds16(gB + (size_t)(J) * 64 * K_TOT + (size_t)(KT) * BK,          \
              (const char*)Bs[P] + (J) * 8192 + wave * 1024)

  // Swizzled fragment read: phys 16B-chunk = (lk + 4*kk) ^ (row&7);
  // all frag rows are (multiple of 8) + l15 -> row&7 == l7.
#define DS8(BASE, ROW, KK)                                                \
  __builtin_bit_cast(bf16x8, *(const short8*)((BASE) + (ROW) * BK +       \
                              (((lk + 4 * (KK)) ^ l7) << 3)))

#define LD_A03(P)                                                         \
  _Pragma("unroll") for (int mi = 0; mi < 4; ++mi) {                      \
    af[mi][0] = DS8(As[P], mi * 32 + wr16l, 0);                           \
    af[mi][1] = DS8(As[P], mi * 32 + wr16l, 1);                           \
  }
#define LD_A47(P)                                                         \
  _Pragma("unroll") for (int mi = 0; mi < 4; ++mi) {                      \
    af[mi][0] = DS8(As[P], (mi + 4) * 32 + wr16l, 0);                     \
    af[mi][1] = DS8(As[P], (mi + 4) * 32 + wr16l, 1);                     \
  }
#define LD_B01(P)                                                         \
  _Pragma("unroll") for (int ni = 0; ni < 2; ++ni) {                      \
    bf[0][ni][0] = DS8(Bs[P], ni * 64 + wc16l, 0);                        \
    bf[0][ni][1] = DS8(Bs[P], ni * 64 + wc16l, 1);                        \
  }
#define LD_B23(P)                                                         \
  _Pragma("unroll") for (int ni = 0; ni < 2; ++ni) {                      \
    bf[1][ni][0] = DS8(Bs[P], (ni + 2) * 64 + wc16l, 0);                  \
    bf[1][ni][1] = DS8(Bs[P], (ni + 2) * 64 + wc16l, 1);                  \
  }

  // Quadrant: 4 mi x 2 ni x 2 kk = 16 MFMA. MH = A half, NS = B slot.
#define MFMA_Q(MH, NS)                                                    \
  __builtin_amdgcn_s_setprio(1);                                          \
  _Pragma("unroll") for (int mi2 = 0; mi2 < 4; ++mi2)                     \
  _Pragma("unroll") for (int ni2 = 0; ni2 < 2; ++ni2)                     \
  _Pragma("unroll") for (int kk2 = 0; kk2 < 2; ++kk2)                     \
      acc[(MH) * 4 + mi2][(NS) * 2 + ni2] =                               \
          __builtin_amdgcn_mfma_f32_16x16x32_bf16(                        \
              af[mi2][kk2], bf[NS][ni2][kk2],                             \
              acc[(MH) * 4 + mi2][(NS) * 2 + ni2], 0, 0, 0);              \
  __builtin_amdgcn_s_setprio(0)

  // ---- prologue: stage t0 (8 gloads), t1 (8 gloads); certify t0; bf01(t0) ----
  STAGE_B(0, 0, 0); STAGE_B(0, 1, 0); STAGE_A(0, 0, 0); STAGE_A(0, 1, 0);
  STAGE_B(0, 2, 0); STAGE_B(0, 3, 0); STAGE_A(0, 2, 0); STAGE_A(0, 3, 0);
  STAGE_B(1, 0, 1); STAGE_B(1, 1, 1); STAGE_A(1, 0, 1); STAGE_A(1, 1, 1);
  STAGE_B(1, 2, 1); STAGE_B(1, 3, 1); STAGE_A(1, 2, 1); STAGE_A(1, 3, 1);
  VMCNT(8);   // t0's 8 landed (per-wave); barrier certifies for all waves
  BAR();
  LD_B01(0);

  // ---- main loop: iteration computes (t: buf0, t+1: buf1), stages (t+2, t+3).
  // Per phase: {ds_reads; stage 1 half-tile; [vmcnt(6) at ph4/ph8 BEFORE the
  // next-tile B read]; BAR; 16 MFMA; BAR}. Staged region always fully read
  // a phase earlier (barrier-certified). vmcnt never drains to 0 mid-loop.
  for (int t = 0; t + 3 < NT; t += 2) {
    // ph1: reads af03(buf0); stage B(t+2)h0
    LD_A03(0);
    STAGE_B(0, 0, t + 2); STAGE_B(0, 1, t + 2);
    BAR(); MFMA_Q(0, 0); BAR();
    // ph2: reads bf23(buf0); stage A(t+2)h0
    LD_B23(0);
    STAGE_A(0, 0, t + 2); STAGE_A(0, 1, t + 2);
    BAR(); MFMA_Q(0, 1); BAR();
    // ph3: reads af47(buf0); stage B(t+2)h1
    LD_A47(0);
    STAGE_B(0, 2, t + 2); STAGE_B(0, 3, t + 2);
    BAR(); MFMA_Q(1, 0); BAR();
    // ph4: vmcnt(6) certifies t+1 (8 drained, 3 staged halves in flight);
    //      then read bf01(buf1, t+1); stage A(t+2)h1
    VMCNT(6);
    LD_B01(1);
    STAGE_A(0, 2, t + 2); STAGE_A(0, 3, t + 2);
    BAR(); MFMA_Q(1, 1); BAR();
    // ph5: reads af03(buf1); stage B(t+3)h0
    LD_A03(1);
    STAGE_B(1, 0, t + 3); STAGE_B(1, 1, t + 3);
    BAR(); MFMA_Q(0, 0); BAR();
    // ph6: reads bf23(buf1); stage A(t+3)h0
    LD_B23(1);
    STAGE_A(1, 0, t + 3); STAGE_A(1, 1, t + 3);
    BAR(); MFMA_Q(0, 1); BAR();
    // ph7: reads af47(buf1); stage B(t+3)h1
    LD_A47(1);
    STAGE_B(1, 2, t + 3); STAGE_B(1, 3, t + 3);
    BAR(); MFMA_Q(1, 0); BAR();
    // ph8: vmcnt(6) certifies t+2; read bf01(buf0, t+2); stage A(t+3)h1
    VMCNT(6);
    LD_B01(0);
    STAGE_A(1, 2, t + 3); STAGE_A(1, 3, t + 3);
    BAR(); MFMA_Q(1, 1); BAR();
  }

  // ---- tail: tiles NT-2 (buf0), NT-1 (buf1), no staging ----
  LD_A03(0); BAR(); MFMA_Q(0, 0); BAR();
  LD_B23(0); BAR(); MFMA_Q(0, 1); BAR();
  LD_A47(0); BAR(); MFMA_Q(1, 0); BAR();
  VMCNT(0);
  LD_B01(1); BAR(); MFMA_Q(1, 1); BAR();
  LD_A03(1); BAR(); MFMA_Q(0, 0); BAR();
  LD_B23(1); BAR(); MFMA_Q(0, 1); BAR();
  LD_A47(1); BAR(); MFMA_Q(1, 0); BAR();
  MFMA_Q(1, 1);

  // ---- epilogue: D mapping col=lane&15, row=(lane>>4)*4+e; fuse scale ----
  const size_t crow0 = (size_t)bm * BM + wr * 16 + (lk << 2);
  const int ccol0 = bn * BN + wc * 16 + l15;
#pragma unroll
  for (int ni = 0; ni < 4; ++ni) {
    const int col = ccol0 + ni * 64;
    const float s = scale[col];
#pragma unroll
    for (int mi = 0; mi < 8; ++mi) {
      const size_t r = crow0 + (size_t)mi * 32;
#pragma unroll
      for (int e = 0; e < 4; ++e)
        C[(r + e) * N_TOT + col] = acc[mi][ni][e] * s;
    }
  }
}

// ---- fallback if workspace too small ----
__global__ void naive_kernel(const float* __restrict__ x,
                             const int* __restrict__ w,
                             const float* __restrict__ s,
                             float* __restrict__ out) {
  int m = blockIdx.y;
  int n = blockIdx.x * 256 + threadIdx.x;
  const float* xr = x + (size_t)m * K_TOT;
  const int* wr = w + (size_t)n * K_TOT;
  float acc = 0.f;
  for (int k = 0; k < K_TOT; ++k) acc += xr[k] * (float)wr[k];
  out[(size_t)m * N_TOT + n] = acc * s[n];
}

extern "C" void kernel_launch(void* const* d_in, const int* in_sizes, int n_in,
                              void* d_out, int out_size, void* d_ws, size_t ws_size,
                              hipStream_t stream) {
  const float* x = (const float*)d_in[0];
  const int* w = (const int*)d_in[1];
  const float* scale = (const float*)d_in[2];
  float* out = (float*)d_out;

  const size_t x_elems = (size_t)M_TOT * K_TOT;
  const size_t w_elems = (size_t)N_TOT * K_TOT;
  const size_t need = (x_elems + w_elems) * sizeof(short);

  if (ws_size < need) {
    dim3 g(N_TOT / 256, M_TOT);
    naive_kernel<<<g, 256, 0, stream>>>(x, w, scale, out);
    return;
  }

  short* xb = (short*)d_ws;
  short* wb = xb + x_elems;

  cvt_x_kernel<<<(int)(x_elems / 8 / 256), 256, 0, stream>>>(
      (const uint4*)x, (short8*)xb);
  cvt_w_kernel<<<(int)(w_elems / 8 / 256), 256, 0, stream>>>(
      (const int4*)w, (short8*)wb);

  wq_gemm_kernel<<<(M_TOT / BM) * (N_TOT / BN), 512, 0, stream>>>(
      xb, wb, scale, out);
}

// Round 8
// 187.733 us; speedup vs baseline: 12.7206x; 1.4195x over previous
//
#include <hip/hip_runtime.h>
#include <hip/hip_bf16.h>
#include <stdint.h>

// out[m][n] = (sum_k x[m][k] * W[n][k]) * scale[n]
// M=8192 (B*S), N=4096 (D_OUT), K=4096 (D_IN)
// x fp32, W int32 (harness materializes integer inputs as int32), scale fp32.
// INT8 path: W is already int8 (exact). x -> per-row symmetric int8
// (sx = amax/127). GEMM via mfma_i32_16x16x64_i8 (2x bf16 rate, half the
// LDS traffic). Dequant epilogue: out = acc_i32 * sx[row] * scale[col].
// Structure: 256x256 tile, BK=64 (i8), 8 waves 2x4, 4-buffer LDS rotation
// (no in-place staging hazard), 2 phases/tile, counted vmcnt(4) before the
// phase barrier, fresh-buffer ds_reads only after it. T1 XCD swizzle,
// chunk-XOR LDS swizzle (both sides), T5 setprio.

#define M_TOT 8192
#define N_TOT 4096
#define K_TOT 4096
#define BM 256
#define BN 256
#define BK 64
#define NT (K_TOT / BK)   // 64 k-tiles

typedef int intx4 __attribute__((ext_vector_type(4)));

// ---- x quantization: one block per row ----
__global__ void quant_x_kernel(const float* __restrict__ x,
                               int* __restrict__ q,       // packed i8, 4/int
                               float* __restrict__ xs) {  // [M] dequant scale
  const int row = blockIdx.x;
  const int tid = threadIdx.x;
  const float4* xr = (const float4*)(x + (size_t)row * K_TOT);
  float4 v[4];
#pragma unroll
  for (int j = 0; j < 4; ++j) v[j] = xr[tid + 256 * j];
  float am = 0.f;
#pragma unroll
  for (int j = 0; j < 4; ++j) {
    am = fmaxf(am, fmaxf(fmaxf(fabsf(v[j].x), fabsf(v[j].y)),
                         fmaxf(fabsf(v[j].z), fabsf(v[j].w))));
  }
#pragma unroll
  for (int off = 32; off >= 1; off >>= 1)
    am = fmaxf(am, __shfl_xor(am, off));
  __shared__ float wmax[4];
  if ((tid & 63) == 0) wmax[tid >> 6] = am;
  __syncthreads();
  am = fmaxf(fmaxf(wmax[0], wmax[1]), fmaxf(wmax[2], wmax[3]));
  const float inv = 127.0f / fmaxf(am, 1e-30f);
  int* qo = q + (size_t)row * (K_TOT / 4);
#pragma unroll
  for (int j = 0; j < 4; ++j) {
    int b0 = __float2int_rn(v[j].x * inv);
    int b1 = __float2int_rn(v[j].y * inv);
    int b2 = __float2int_rn(v[j].z * inv);
    int b3 = __float2int_rn(v[j].w * inv);
    qo[tid + 256 * j] =
        (b0 & 255) | ((b1 & 255) << 8) | ((b2 & 255) << 16) | (b3 << 24);
  }
  if (tid == 0) xs[row] = am * (1.0f / 127.0f);
}

// ---- W repack: int32 -> i8 (exact) ----
__global__ void pack_w_kernel(const int4* __restrict__ in, int4* __restrict__ out) {
  const int i = blockIdx.x * blockDim.x + threadIdx.x;  // 16 ints -> 16 bytes
  int4 r0 = in[4 * i], r1 = in[4 * i + 1], r2 = in[4 * i + 2], r3 = in[4 * i + 3];
  int4 o;
  o.x = (r0.x & 255) | ((r0.y & 255) << 8) | ((r0.z & 255) << 16) | (r0.w << 24);
  o.y = (r1.x & 255) | ((r1.y & 255) << 8) | ((r1.z & 255) << 16) | (r1.w << 24);
  o.z = (r2.x & 255) | ((r2.y & 255) << 8) | ((r2.z & 255) << 16) | (r2.w << 24);
  o.w = (r3.x & 255) | ((r3.y & 255) << 8) | ((r3.z & 255) << 16) | (r3.w << 24);
  out[i] = o;
}

// ---- async global->LDS (16B per lane, wave-uniform dest + lane*16) ----
__device__ __forceinline__ void gload_lds16(const void* g, const void* l) {
  const __attribute__((address_space(1))) void* gp =
      reinterpret_cast<const __attribute__((address_space(1))) void*>(
          reinterpret_cast<uintptr_t>(g));
  __attribute__((address_space(3))) void* lp =
      reinterpret_cast<__attribute__((address_space(3))) void*>(
          (uint32_t)reinterpret_cast<uintptr_t>(l));
  __builtin_amdgcn_global_load_lds(gp, lp, 16, 0, 0);
}

#define BAR() __builtin_amdgcn_s_barrier()
#define VMCNT(N) asm volatile("s_waitcnt vmcnt(" #N ")" ::: "memory")

// ---- main GEMM: i8, 256x256 tile, 8 waves (2x4), 2 phases/k-tile ----
__global__ __launch_bounds__(512, 2)
void wq_gemm_kernel(const char* __restrict__ A,     // [M][K] i8 (quantized x)
                    const char* __restrict__ B,     // [N][K] i8 (W rows)
                    const float* __restrict__ XS,   // [M] x dequant scale
                    const float* __restrict__ scale,// [N]
                    float* __restrict__ C) {        // [M][N]
  // 4-buffer rotation: [buf][256 rows][64 B] per operand = 4 x 16 KiB x 2.
  __shared__ __align__(16) char As[4][BM * BK];
  __shared__ __align__(16) char Bs[4][BN * BK];

  // XCD-aware block swizzle (nwg=512, divisible by 8)
  const int nb = gridDim.x;
  const int swz = (blockIdx.x & 7) * (nb >> 3) + (blockIdx.x >> 3);
  const int bm = swz >> 4;        // M/BM = 32
  const int bn = swz & 15;        // N/BN = 16

  const int tid = threadIdx.x;
  const int wave = tid >> 6, lane = tid & 63;
  const int wr = wave >> 2, wc = wave & 3;   // 2 x 4 wave grid
  const int l15 = lane & 15, lk = lane >> 4;
  const int wr16l = wr * 16 + l15;
  const int wc16l = wc * 16 + l15;
  const int rchunk = (lk ^ (l15 & 3)) << 4;  // swizzled 16B chunk (bytes)

  intx4 acc[8][4] = {};
  intx4 af[4], bf[4];

  // Staging: one gload = 512 threads x 16B = 128 rows x 64B; 2 per operand
  // per tile. LDS dest linear; global source chunk pre-swizzled (involution).
  const int srow = tid >> 2;                  // 0..127
  const int sc = (tid & 3) ^ (srow & 3);      // source 16B chunk
  const char* gA = A + (size_t)(bm * BM + srow) * K_TOT + sc * 16;
  const char* gB = B + (size_t)(bn * BN + srow) * K_TOT + sc * 16;

#define STAGE_A(P, J, KT)                                                 \
  gload_lds16(gA + (size_t)(J) * 128 * K_TOT + (size_t)(KT) * BK,         \
              As[P] + (J) * 8192 + wave * 1024)
#define STAGE_B(P, J, KT)                                                 \
  gload_lds16(gB + (size_t)(J) * 128 * K_TOT + (size_t)(KT) * BK,         \
              Bs[P] + (J) * 8192 + wave * 1024)

  // Fragment read: row R, swizzled chunk; all frag rows have R&3 == l15&3.
#define DS16(BASE, ROW)                                                   \
  *(const intx4*)((BASE) + (ROW) * BK + rchunk)

#define LD_A03(P)                                                         \
  _Pragma("unroll") for (int mi = 0; mi < 4; ++mi)                        \
      af[mi] = DS16(As[P], mi * 32 + wr16l);
#define LD_A47(P)                                                         \
  _Pragma("unroll") for (int mi = 0; mi < 4; ++mi)                        \
      af[mi] = DS16(As[P], (mi + 4) * 32 + wr16l);
#define LD_B(P)                                                           \
  _Pragma("unroll") for (int ni = 0; ni < 4; ++ni)                        \
      bf[ni] = DS16(Bs[P], ni * 64 + wc16l);

  // Half-tile: 4 mi x 4 ni = 16 MFMA (K=64 each).
#define MFMA_H(H)                                                         \
  __builtin_amdgcn_s_setprio(1);                                          \
  _Pragma("unroll") for (int mi2 = 0; mi2 < 4; ++mi2)                     \
  _Pragma("unroll") for (int ni2 = 0; ni2 < 4; ++ni2)                     \
      acc[(H) * 4 + mi2][ni2] = __builtin_amdgcn_mfma_i32_16x16x64_i8(    \
          af[mi2], bf[ni2], acc[(H) * 4 + mi2][ni2], 0, 0, 0);            \
  __builtin_amdgcn_s_setprio(0)

  // Tile: ph0 {read A03+B (8), stage B(t+2) (2), BAR, 16 MFMA, BAR}
  //       ph1 {read A47 (4), stage A(t+2) (2), VMCNT(4), BAR, 16 MFMA, BAR}
  // Fresh-buffer reads happen only in the phase AFTER every wave's vmcnt +
  // barrier -> cross-wave staging certified. vmcnt never 0 mid-loop.
#define TILE(P, T)                                                        \
  do {                                                                    \
    LD_A03(P);                                                            \
    LD_B(P);                                                              \
    STAGE_B(((P) + 2) & 3, 0, (T) + 2); STAGE_B(((P) + 2) & 3, 1, (T) + 2);\
    BAR();                                                                \
    MFMA_H(0);                                                            \
    BAR();                                                                \
    LD_A47(P);                                                            \
    STAGE_A(((P) + 2) & 3, 0, (T) + 2); STAGE_A(((P) + 2) & 3, 1, (T) + 2);\
    VMCNT(4);                                                             \
    BAR();                                                                \
    MFMA_H(1);                                                            \
    BAR();                                                                \
  } while (0)

  // ---- prologue: stage t0 -> buf0, t1 -> buf1; certify t0 ----
  STAGE_B(0, 0, 0); STAGE_B(0, 1, 0); STAGE_A(0, 0, 0); STAGE_A(0, 1, 0);
  STAGE_B(1, 0, 1); STAGE_B(1, 1, 1); STAGE_A(1, 0, 1); STAGE_A(1, 1, 1);
  VMCNT(4);
  BAR();

  // ---- main loop: tiles 0..NT-5 stage t+2 unconditionally ----
  for (int t = 0; t + 7 < NT; t += 4) {
    TILE(0, t);
    TILE(1, t + 1);
    TILE(2, t + 2);
    TILE(3, t + 3);
  }
  // tail: tiles NT-4, NT-3 still stage; NT-2 drains; NT-1 plain.
  TILE(0, NT - 4);
  TILE(1, NT - 3);
  // tile NT-2 (buf2): no staging; certify NT-1 with vmcnt(0).
  LD_A03(2); LD_B(2); BAR(); MFMA_H(0); BAR();
  LD_A47(2); VMCNT(0); BAR(); MFMA_H(1); BAR();
  // tile NT-1 (buf3)
  LD_A03(3); LD_B(3); BAR(); MFMA_H(0); BAR();
  LD_A47(3);
  MFMA_H(1);
#undef TILE

  // ---- epilogue: D mapping col=lane&15, row=(lane>>4)*4+e; dequant ----
  const size_t crow0 = (size_t)bm * BM + wr * 16 + (lk << 2);
  const int ccol0 = bn * BN + wc * 16 + l15;
  float sc4[4];
#pragma unroll
  for (int ni = 0; ni < 4; ++ni) sc4[ni] = scale[ccol0 + ni * 64];
#pragma unroll
  for (int mi = 0; mi < 8; ++mi) {
#pragma unroll
    for (int e = 0; e < 4; ++e) {
      const size_t r = crow0 + (size_t)mi * 32 + e;
      const float xr = XS[r];
#pragma unroll
      for (int ni = 0; ni < 4; ++ni)
        C[r * N_TOT + ccol0 + ni * 64] = (float)acc[mi][ni][e] * xr * sc4[ni];
    }
  }
}

// ---- fallback if workspace too small (insurance; slow but correct) ----
__global__ void naive_kernel(const float* __restrict__ x,
                             const int* __restrict__ w,
                             const float* __restrict__ s,
                             float* __restrict__ out) {
  int m = blockIdx.y;
  int n = blockIdx.x * 256 + threadIdx.x;
  const float* xr = x + (size_t)m * K_TOT;
  const int* wr = w + (size_t)n * K_TOT;
  float acc = 0.f;
  for (int k = 0; k < K_TOT; ++k) acc += xr[k] * (float)wr[k];
  out[(size_t)m * N_TOT + n] = acc * s[n];
}

extern "C" void kernel_launch(void* const* d_in, const int* in_sizes, int n_in,
                              void* d_out, int out_size, void* d_ws, size_t ws_size,
                              hipStream_t stream) {
  const float* x = (const float*)d_in[0];
  const int* w = (const int*)d_in[1];
  const float* scale = (const float*)d_in[2];
  float* out = (float*)d_out;

  const size_t x_elems = (size_t)M_TOT * K_TOT;   // i8 bytes
  const size_t w_elems = (size_t)N_TOT * K_TOT;   // i8 bytes
  const size_t need = x_elems + w_elems + M_TOT * sizeof(float);

  if (ws_size < need) {
    dim3 g(N_TOT / 256, M_TOT);
    naive_kernel<<<g, 256, 0, stream>>>(x, w, scale, out);
    return;
  }

  char* qx = (char*)d_ws;
  char* qw = qx + x_elems;
  float* xs = (float*)(qw + w_elems);

  quant_x_kernel<<<M_TOT, 256, 0, stream>>>(x, (int*)qx, xs);
  pack_w_kernel<<<(int)(w_elems / 16 / 256), 256, 0, stream>>>(
      (const int4*)w, (int4*)qw);

  wq_gemm_kernel<<<(M_TOT / BM) * (N_TOT / BN), 512, 0, stream>>>(
      qx, qw, xs, scale, out);
}